// Round 7
// baseline (363.390 us; speedup 1.0000x reference)
//
#include <hip/hip_runtime.h>
#include <hip/hip_bf16.h>
#include <stdint.h>
#include <stddef.h>

typedef unsigned short u16;
using bf16x8 = __attribute__((ext_vector_type(8))) short;   // 8 bf16 = 4 VGPR
using f32x4  = __attribute__((ext_vector_type(4))) float;
using f32x16 = __attribute__((ext_vector_type(16))) float;

#define DEVFN static __device__ __forceinline__

DEVFN u16 f2b(float f){ __hip_bfloat16 h = __float2bfloat16(f); return *reinterpret_cast<u16*>(&h); }
DEVFN float b2f(u16 u){ __hip_bfloat16 h; *reinterpret_cast<u16*>(&h) = u; return __bfloat162float(h); }
DEVFN float ex2(float x){ float r; asm("v_exp_f32 %0, %1" : "=v"(r) : "v"(x)); return r; }

DEVFN void gload_lds16(const void* g, void* l){
  __builtin_amdgcn_global_load_lds(
      (const __attribute__((address_space(1))) void*)g,
      (__attribute__((address_space(3))) void*)l, 16, 0, 0);
}

// ---------------- dtype detect: freqs_cos[0]==1.0f -> f32 (0x3F800000), bf16 pair -> 0x3F803F80
__global__ void detect_k(const uint32_t* __restrict__ fc_raw, uint32_t* __restrict__ flag){
  if (threadIdx.x == 0 && blockIdx.x == 0)
    flag[0] = (fc_raw[0] == 0x3F800000u) ? 1u : 0u;
}

// ---------------- freqs -> f32 table ----------------
__global__ __launch_bounds__(256) void cvtf_k(const void* __restrict__ in, float* __restrict__ out,
                                              int n, const uint32_t* __restrict__ flag){
  const int i = blockIdx.x*256 + threadIdx.x;
  if (i >= n) return;
  if (flag[0]) out[i] = ((const float*)in)[i];
  else         out[i] = b2f(((const u16*)in)[i]);
}

// ---------------- x -> bf16 (8 elems/thread) ----------------
__global__ __launch_bounds__(256) void cvtx_k(const void* __restrict__ in, u16* __restrict__ out,
                                              int n8, const uint32_t* __restrict__ flag){
  const int i = blockIdx.x*256 + threadIdx.x;
  if (i >= n8) return;
  __align__(16) u16 e[8];
  if (flag[0]){
    const float* f = (const float*)in + (size_t)i*8;
    float4 a = *(const float4*)f, b = *(const float4*)(f+4);
    e[0]=f2b(a.x); e[1]=f2b(a.y); e[2]=f2b(a.z); e[3]=f2b(a.w);
    e[4]=f2b(b.x); e[5]=f2b(b.y); e[6]=f2b(b.z); e[7]=f2b(b.w);
  } else {
    *(uint4*)e = *((const uint4*)in + i);
  }
  *(uint4*)(out + (size_t)i*8) = *(const uint4*)e;
}

// ---------------- weight transpose (+dtype cvt): in (R x C) -> out bf16 (C x R) ----------------
__global__ __launch_bounds__(512) void wtrans_k(const void* __restrict__ in, u16* __restrict__ out,
                                                int C, int R, const uint32_t* __restrict__ flag){
  __shared__ __align__(16) u16 tile[64][72];
  const int r0 = blockIdx.y*64, c0 = blockIdx.x*64;
  const int t = threadIdx.x, r = t>>3, cs = (t&7)*8;
  __align__(16) u16 e[8];
  if (flag[0]){
    const float* f = (const float*)in + (size_t)(r0+r)*C + c0 + cs;
    float4 a = *(const float4*)f, b = *(const float4*)(f+4);
    e[0]=f2b(a.x); e[1]=f2b(a.y); e[2]=f2b(a.z); e[3]=f2b(a.w);
    e[4]=f2b(b.x); e[5]=f2b(b.y); e[6]=f2b(b.z); e[7]=f2b(b.w);
  } else {
    *(uint4*)e = *(const uint4*)((const u16*)in + (size_t)(r0+r)*C + c0 + cs);
  }
#pragma unroll
  for (int j=0;j<8;j++) tile[cs+j][r] = e[j];
  __syncthreads();
  uint4 o = *(const uint4*)&tile[r][cs];
  *(uint4*)(out + (size_t)(c0+r)*R + r0 + cs) = o;
}

// ---------------- V transpose: qkv v-slice (t x d) -> vT[(b*8+g)*128 + d][t] ----------------
__global__ __launch_bounds__(512) void vtrans_k(const u16* __restrict__ qkv, u16* __restrict__ vT){
  __shared__ __align__(16) u16 tile[64][72];
  const int z = blockIdx.z, b = z>>3, g = z&7;
  const u16* in = qkv + (size_t)(b*2048)*4096 + 3072 + g*128;
  u16* out = vT + (size_t)z*128*2048;
  const int r0 = blockIdx.y*64, c0 = blockIdx.x*64;   // r0 over t, c0 over d
  const int t = threadIdx.x, r = t>>3, cs = (t&7)*8;
  uint4 v = *(const uint4*)(in + (size_t)(r0+r)*4096 + c0 + cs);
  const u16* e = (const u16*)&v;
#pragma unroll
  for (int j=0;j<8;j++) tile[cs+j][r] = e[j];
  __syncthreads();
  uint4 o = *(const uint4*)&tile[r][cs];
  *(uint4*)(out + (size_t)(c0+r)*2048 + r0 + cs) = o;
}

// ---------------- RoPE in-place; q additionally pre-scaled by 1/sqrt(D)*log2(e) ----------------
// (folds the softmax scale AND the exp->exp2 conversion into the q matrix for free)
__global__ __launch_bounds__(256) void rope_k(u16* qkv, const float* __restrict__ fc,
                                              const float* __restrict__ fs){
  const int idx = blockIdx.x*256 + threadIdx.x;    // 4096 rows * 1536 pairs
  const int row = idx / 1536;
  const int p   = idx % 1536;
  const int col0 = p*2;
  const int t = row & 2047;
  const int i = p & 63;
  uint32_t* ptr = (uint32_t*)(qkv + (size_t)row*4096 + col0);
  uint32_t u = *ptr;
  float x0 = b2f((u16)(u & 0xffff));
  float x1 = b2f((u16)(u >> 16));
  float c = fc[t*64+i], s = fs[t*64+i];
  float o0 = x0*c - x1*s;
  float o1 = x0*s + x1*c;
  if (col0 < 2048){                                  // q part only
    const float SCL = 0.08838834764831845f * 1.4426950408889634f;
    o0 *= SCL; o1 *= SCL;
  }
  *ptr = (uint32_t)f2b(o0) | ((uint32_t)f2b(o1) << 16);
}

// ---------------- GEMM: C(MxN) = A(MxK) * Bt(NxK)^T, bf16 in, fp32 accum ----------------
__global__ __launch_bounds__(256) void gemm_bt(const u16* __restrict__ A, const u16* __restrict__ Bt,
                                               void* __restrict__ Cv, int M, int N, int K,
                                               const uint32_t* __restrict__ flag, int fin){
  __shared__ __align__(16) u16 Al[2][128*32];
  __shared__ __align__(16) u16 Bl[2][128*32];
  const int nwg_x = N>>7;
  int wg = blockIdx.x;
  {
    const int nwg = gridDim.x;
    const int cpx = nwg >> 3;
    wg = (wg & 7)*cpx + (wg >> 3);
  }
  const int tm = (wg / nwg_x)*128, tn = (wg % nwg_x)*128;
  const int tid = threadIdx.x, w = tid>>6, l = tid&63, lr = l&15, lg = l>>4;
  const int wr = w>>1, wc = w&1;

  f32x4 acc[4][4] = {};

  auto stage = [&](int buf, int kk){
#pragma unroll
    for (int issue=0; issue<2; ++issue){
      const int c = issue*256 + w*64 + l;
      const int r = c>>2, sl = c&3;
      const int gch = sl ^ (r&3);
      gload_lds16(A  + (size_t)(tm + r)*K + kk + gch*8, &Al[buf][(issue*256 + w*64)*8]);
      gload_lds16(Bt + (size_t)(tn + r)*K + kk + gch*8, &Bl[buf][(issue*256 + w*64)*8]);
    }
  };

  stage(0, 0);
  __syncthreads();
  const int nk = K>>5;
  for (int kt=0; kt<nk; ++kt){
    if (kt+1 < nk) stage((kt+1)&1, (kt+1)*32);
    const u16* Ab = Al[kt&1];
    const u16* Bb = Bl[kt&1];
    bf16x8 a[4], b[4];
#pragma unroll
    for (int mi=0;mi<4;mi++){
      const int rr = wr*64 + mi*16 + lr;
      a[mi] = *(const bf16x8*)&Ab[rr*32 + ((lg ^ (rr&3))*8)];
    }
#pragma unroll
    for (int ni=0;ni<4;ni++){
      const int rr = wc*64 + ni*16 + lr;
      b[ni] = *(const bf16x8*)&Bb[rr*32 + ((lg ^ (rr&3))*8)];
    }
#pragma unroll
    for (int mi=0;mi<4;mi++)
#pragma unroll
      for (int ni=0;ni<4;ni++)
        acc[mi][ni] = __builtin_amdgcn_mfma_f32_16x16x32_bf16(a[mi], b[ni], acc[mi][ni], 0,0,0);
    __syncthreads();
  }
  const bool of32 = fin && (flag[0] != 0);
#pragma unroll
  for (int mi=0;mi<4;mi++)
#pragma unroll
    for (int ni=0;ni<4;ni++)
#pragma unroll
      for (int reg=0;reg<4;reg++){
        const int row = tm + wr*64 + mi*16 + lg*4 + reg;
        const int col = tn + wc*64 + ni*16 + lr;
        const size_t idx = (size_t)row*N + col;
        const float v = acc[mi][ni][reg];
        if (of32) ((float*)Cv)[idx] = v;
        else      ((u16*)Cv)[idx]   = f2b(v);
      }
}

// ---------------- causal GQA flash attention v4: barrier-free, LDS-free ----------------
// K/V per (b,g) = 1MB, L2-resident (shared by 128 wave-tasks) -> read MFMA fragments
// DIRECTLY from global; no LDS staging, no __syncthreads, no bank conflicts.
// 256 blocks x 4 waves = 1024 independent waves (1/SIMD, every SIMD busy).
// Wave task: 32-row q-tile pair (v, 63-v) -> uniform 33 kv-64 steps.
// g = blockIdx&7 -> XCD-local K/V slice (2MB/XCD in L2).
// Softmax in log2 domain (q pre-scaled by scale*log2e in rope_k; raw v_exp_f32).
__global__ __launch_bounds__(256, 1) void attn_k(const u16* __restrict__ qkv,
                                                 const u16* __restrict__ vT,
                                                 u16* __restrict__ y){
  const int i0 = blockIdx.x;
  const int g  = i0 & 7;
  const int j  = i0 >> 3;                    // 0..31
  const int w  = threadIdx.x >> 6;           // 0..3
  const int l  = threadIdx.x & 63;
  const int lq = l & 31, hi = l >> 5;
  const int jj = j*4 + w;                    // 0..127 task-in-g
  const int v  = jj & 31;                    // pair id
  const int hl = (jj >> 5) & 1;
  const int b  = jj >> 6;
  const int h  = g*2 + hl;

  const u16* kg = qkv + (size_t)(b*2048)*4096 + 2048 + g*128;
  const u16* vg = vT  + (size_t)(b*8+g)*128*2048;

#pragma unroll 1
  for (int ph=0; ph<2; ++ph){
    const int qt   = ph ? (63 - v) : v;      // 32-row q-tile index
    const int nkt  = (qt>>1) + 1;            // kv-64 steps
    const int qmin = qt*32;
    const int qrow = qmin + lq;

    bf16x8 qf[8];
    {
      const u16* qp = qkv + (size_t)(b*2048 + qmin + lq)*4096 + h*128 + hi*8;
#pragma unroll
      for (int ds=0; ds<8; ++ds) qf[ds] = *(const bf16x8*)(qp + ds*16);
    }
    f32x16 yacc[4];
#pragma unroll
    for (int dt=0; dt<4; ++dt)
#pragma unroll
      for (int r=0; r<16; ++r) yacc[dt][r] = 0.f;
    float mrow = -1e30f, lsum = 0.f;

#pragma unroll 1
    for (int kt=0; kt<nkt; ++kt){
      const int kbase = kt*64;

      // ---- S^T = K * Q^T : 16 MFMA 32x32x16, K-frags straight from L2 ----
      f32x16 sc[2];
#pragma unroll
      for (int t=0;t<2;t++)
#pragma unroll
        for (int r=0;r<16;r++) sc[t][r] = 0.f;
      __builtin_amdgcn_s_setprio(1);
#pragma unroll
      for (int t=0; t<2; ++t){
        const u16* kp = kg + (size_t)(kbase + t*32 + lq)*4096 + hi*8;
#pragma unroll
        for (int ds=0; ds<8; ++ds){
          const bf16x8 kf = *(const bf16x8*)(kp + ds*16);
          sc[t] = __builtin_amdgcn_mfma_f32_32x32x16_bf16(kf, qf[ds], sc[t], 0,0,0);
        }
      }
      __builtin_amdgcn_s_setprio(0);

      // ---- lane-local online softmax, log2 domain ----
      const bool needmask = (kbase + 63) > qmin;
      float pmax = -1e30f;
#pragma unroll
      for (int t=0;t<2;t++)
#pragma unroll
        for (int r=0;r<16;r++){
          float vv = sc[t][r];
          if (needmask){
            const int kp2 = kbase + t*32 + (r&3) + 8*(r>>2) + 4*hi;
            if (kp2 > qrow) vv = -1e30f;
          }
          sc[t][r] = vv;
          pmax = fmaxf(pmax, vv);
        }
      pmax = fmaxf(pmax, __shfl_xor(pmax, 32));
      if (!__all(pmax <= mrow + 8.f)){       // T13 defer-max (2^8 headroom)
        const float mnew = fmaxf(mrow, pmax);
        const float corr = ex2(mrow - mnew);
        mrow = mnew; lsum *= corr;
#pragma unroll
        for (int dt=0;dt<4;dt++)
#pragma unroll
          for (int r=0;r<16;r++) yacc[dt][r] *= corr;
      }
      float lsub = 0.f;
#pragma unroll
      for (int t=0;t<2;t++)
#pragma unroll
        for (int r=0;r<16;r++){
          const float p = ex2(sc[t][r] - mrow);
          sc[t][r] = p; lsub += p;
        }
      lsub += __shfl_xor(lsub, 32);
      lsum += lsub;

      // ---- P -> PV B-fragments (pack + half-wave exchange) ----
      __align__(16) uint32_t pw[4][4];       // [ks][word]
#pragma unroll
      for (int t=0;t<2;t++)
#pragma unroll
        for (int half=0; half<2; ++half){
          const int q8 = half*8;
          uint32_t X0 = (uint32_t)f2b(sc[t][q8+0]) | ((uint32_t)f2b(sc[t][q8+1])<<16);
          uint32_t X1 = (uint32_t)f2b(sc[t][q8+2]) | ((uint32_t)f2b(sc[t][q8+3])<<16);
          uint32_t X2 = (uint32_t)f2b(sc[t][q8+4]) | ((uint32_t)f2b(sc[t][q8+5])<<16);
          uint32_t X3 = (uint32_t)f2b(sc[t][q8+6]) | ((uint32_t)f2b(sc[t][q8+7])<<16);
          const uint32_t pX0 = (uint32_t)__shfl_xor((int)X0, 32);
          const uint32_t pX1 = (uint32_t)__shfl_xor((int)X1, 32);
          const uint32_t pX2 = (uint32_t)__shfl_xor((int)X2, 32);
          const uint32_t pX3 = (uint32_t)__shfl_xor((int)X3, 32);
          const int ks = t*2 + half;
          pw[ks][0] = hi ? pX2 : X0;
          pw[ks][1] = hi ? pX3 : X1;
          pw[ks][2] = hi ? X2 : pX0;
          pw[ks][3] = hi ? X3 : pX1;
        }

      // ---- O^T += V^T * P^T : 16 MFMA 32x32x16, V-frags straight from L2 ----
      __builtin_amdgcn_s_setprio(1);
#pragma unroll
      for (int dt=0; dt<4; ++dt){
        const u16* vp = vg + (size_t)(dt*32 + lq)*2048 + kbase + hi*8;
#pragma unroll
        for (int ks=0; ks<4; ++ks){
          const bf16x8 vf = *(const bf16x8*)(vp + ks*16);
          yacc[dt] = __builtin_amdgcn_mfma_f32_32x32x16_bf16(vf, *(const bf16x8*)&pw[ks][0], yacc[dt], 0,0,0);
        }
      }
      __builtin_amdgcn_s_setprio(0);
    }

    // ---- normalize + store (lane owns q-row qmin+lq; hi partitions d) ----
    const float inv = 1.f / lsum;
    u16* yp = y + (size_t)(b*2048 + qmin + lq)*2048 + h*128;
#pragma unroll
    for (int dt=0; dt<4; ++dt)
#pragma unroll
      for (int rq=0; rq<4; ++rq){
        const int d0 = dt*32 + rq*8 + hi*4;
        uint32_t lo = (uint32_t)f2b(yacc[dt][rq*4+0]*inv) | ((uint32_t)f2b(yacc[dt][rq*4+1]*inv)<<16);
        uint32_t hi2= (uint32_t)f2b(yacc[dt][rq*4+2]*inv) | ((uint32_t)f2b(yacc[dt][rq*4+3]*inv)<<16);
        *(uint2*)(yp + d0) = make_uint2(lo, hi2);
      }
  }
}

// ---------------- host ----------------
extern "C" void kernel_launch(void* const* d_in, const int* in_sizes, int n_in,
                              void* d_out, int out_size, void* d_ws, size_t ws_size,
                              hipStream_t stream){
  char* ws = (char*)d_ws;
  const size_t MB = 1048576;
  uint32_t* flag = (uint32_t*)(ws);
  float* fcF = (float*)(ws + 1*MB);
  float* fsF = (float*)(ws + 1*MB + 524288);
  u16* xb   = (u16*)(ws + 2*MB);           // 16 MB (reused as yb after gemm1)
  u16* waT  = (u16*)(ws + 18*MB);          // 16 MB
  u16* wpT  = (u16*)(ws + 34*MB);          // 8 MB
  u16* qkvb = (u16*)(ws + 42*MB);          // 32 MB
  u16* vTb  = (u16*)(ws + 74*MB);          // 8 MB
  u16* yb   = xb;

  detect_k<<<1, 64, 0, stream>>>((const uint32_t*)d_in[3], flag);
  cvtf_k  <<<512, 256, 0, stream>>>(d_in[3], fcF, 131072, flag);
  cvtf_k  <<<512, 256, 0, stream>>>(d_in[4], fsF, 131072, flag);
  cvtx_k  <<<4096, 256, 0, stream>>>(d_in[0], xb, 1048576, flag);
  wtrans_k<<<dim3(64,32,1), 512, 0, stream>>>(d_in[1], waT, 4096, 2048, flag);
  wtrans_k<<<dim3(32,32,1), 512, 0, stream>>>(d_in[2], wpT, 2048, 2048, flag);
  gemm_bt <<<dim3(1024,1,1), 256, 0, stream>>>(xb, waT, qkvb, 4096, 4096, 2048, flag, 0);
  rope_k  <<<dim3(24576,1,1), 256, 0, stream>>>(qkvb, fcF, fsF);
  vtrans_k<<<dim3(2,32,16), 512, 0, stream>>>(qkvb, vTb);
  attn_k  <<<dim3(256,1,1), 256, 0, stream>>>(qkvb, vTb, yb);
  gemm_bt <<<dim3(512,1,1), 256, 0, stream>>>(yb, wpT, d_out, 4096, 2048, 2048, flag, 1);
}